// Round 1
// baseline (1441.416 us; speedup 1.0000x reference)
//
#include <hip/hip_runtime.h>
#include <math.h>

#pragma clang fp contract(off)

#define A_TOTAL 196416
#define BATCH 8
#define KTOT 4576
#define NLEV 5

static __device__ const int d_aoff[NLEV] = {0, 147456, 184320, 193536, 195840};
static __device__ const int d_n[NLEV]    = {147456, 36864, 9216, 2304, 576};
static __device__ const int d_k[NLEV]    = {1000, 1000, 1000, 1000, 576};
static __device__ const int d_koff[NLEV] = {0, 1000, 2000, 3000, 4000};

// monotone map: f32 -> u32 preserving order (no NaNs in this data)
__device__ inline unsigned int mono(float f) {
  unsigned int u = __float_as_uint(f);
  return (u & 0x80000000u) ? ~u : (u | 0x80000000u);
}

// in-LDS bitonic ascending sort; all threads of the block must call
template <typename T>
__device__ inline void bitonic_sort(T* arr, int N, int tid, int nth) {
  for (int size = 2; size <= N; size <<= 1) {
    for (int stride = size >> 1; stride > 0; stride >>= 1) {
      __syncthreads();
      for (int e = tid; e < N; e += nth) {
        int partner = e ^ stride;
        if (partner > e) {
          T a = arr[e], b2 = arr[partner];
          bool up = ((e & size) == 0);
          if (up ? (a > b2) : (a < b2)) { arr[e] = b2; arr[partner] = a; }
        }
      }
    }
  }
  __syncthreads();
}

// ---------------------------------------------------------------------------
// K1: per (batch, level) exact top-k (lax.top_k semantics: value desc, idx asc)
// 4-pass MSB radix-histogram select, then bitonic rank-sort of the k winners.
// ---------------------------------------------------------------------------
__global__ __launch_bounds__(1024) void k_topk(const float* __restrict__ obj,
                                               int* __restrict__ sel_idx,
                                               float* __restrict__ maxv) {
  int bx = blockIdx.x;
  int b = bx / NLEV, l = bx % NLEV;
  int tid = threadIdx.x;
  if (tid == 0 && bx < BATCH) maxv[bx] = 0.0f;  // init for K2's atomicMax (coords >= 0)
  const int aoff = d_aoff[l], n = d_n[l], k = d_k[l], koff = d_koff[l];
  const float* ob = obj + (size_t)b * A_TOTAL + aoff;

  __shared__ int hist[256];
  __shared__ unsigned int s_prefix;
  __shared__ int s_need, s_cntgt, s_cnteq;
  __shared__ unsigned long long cand[1024];
  __shared__ unsigned int ties[2048];

  if (tid == 0) { s_prefix = 0u; s_need = k; }
  __syncthreads();

  for (int p = 3; p >= 0; --p) {
    if (tid < 256) hist[tid] = 0;
    __syncthreads();
    unsigned int mask_hi = (p == 3) ? 0u : (0xFFFFFFFFu << (8 * (p + 1)));
    unsigned int pref = s_prefix;
    for (int i = tid; i < n; i += 1024) {
      unsigned int key = mono(ob[i]);
      if ((key & mask_hi) == pref)
        atomicAdd(&hist[(key >> (8 * p)) & 255], 1);
    }
    __syncthreads();
    if (tid == 0) {
      int cum = 0, need = s_need, d;
      for (d = 255; d >= 0; --d) {
        int c = hist[d];
        if (cum + c >= need) { s_need = need - cum; break; }
        cum += c;
      }
      s_prefix = pref | ((unsigned int)d << (8 * p));
    }
    __syncthreads();
  }
  unsigned int T = s_prefix;  // exact key of the k-th largest
  int r = s_need;             // how many ties at T to take (smallest indices)

  if (tid == 0) { s_cntgt = 0; s_cnteq = 0; }
  __syncthreads();
  for (int i = tid; i < n; i += 1024) {
    unsigned int key = mono(ob[i]);
    if (key > T) {
      int slot = atomicAdd(&s_cntgt, 1);
      if (slot < 1024)
        cand[slot] = ((unsigned long long)key << 32) | (unsigned int)(~(unsigned int)i);
    } else if (key == T) {
      int slot = atomicAdd(&s_cnteq, 1);
      if (slot < 2048) ties[slot] = (unsigned int)i;
    }
  }
  __syncthreads();
  int cgt = min(s_cntgt, 1024);   // == k - r by construction
  int ne = min(s_cnteq, 2048);
  for (int i = tid; i < 2048; i += 1024) if (i >= ne) ties[i] = 0xFFFFFFFFu;
  __syncthreads();
  bitonic_sort(ties, 2048, tid, 1024);   // ascending index
  if (tid < r && cgt + tid < 1024)
    cand[cgt + tid] = ((unsigned long long)T << 32) | (unsigned int)(~ties[tid]);
  for (int i = tid; i < 1024; i += 1024) if (i >= cgt + r) cand[i] = 0ull;
  __syncthreads();
  bitonic_sort(cand, 1024, tid, 1024);   // ascending composite
  if (tid < k) {
    unsigned long long e = cand[1023 - tid];               // rank tid (desc value, asc idx)
    unsigned int idx = ~(unsigned int)(e & 0xFFFFFFFFull);
    sel_idx[b * KTOT + koff + tid] = aoff + (int)idx;
  }
}

// ---------------------------------------------------------------------------
// K2: decode + clip + sigmoid + validity for the selected 8x4576 anchors
// ---------------------------------------------------------------------------
__global__ void k_decode(const float* __restrict__ obj,
                         const float* __restrict__ deltas,
                         const float* __restrict__ anchors,
                         const int* __restrict__ sel_idx,
                         float* __restrict__ boxes,
                         float* __restrict__ sprime,
                         float* __restrict__ maxv) {
  int g = blockIdx.x * blockDim.x + threadIdx.x;
  if (g >= BATCH * KTOT) return;
  int b = g / KTOT;
  int gidx = sel_idx[g];
  float o = obj[(size_t)b * A_TOTAL + gidx];
  const float* dl = deltas + ((size_t)b * A_TOTAL + gidx) * 4;
  const float* an = anchors + (size_t)gidx * 4;
  float a0 = an[0], a1 = an[1], a2 = an[2], a3 = an[3];
  float wa = a2 - a0, ha = a3 - a1;
  float cxa = a0 + 0.5f * wa, cya = a1 + 0.5f * ha;
  float dx = dl[0], dy = dl[1];
  const float CLIPV = 4.135166556742356f;  // log(1000/16)
  float dw = fminf(dl[2], CLIPV), dh = fminf(dl[3], CLIPV);
  float pcx = dx * wa + cxa;               // contract(off): separate mul+add like numpy
  float pcy = dy * ha + cya;
  float pw = (float)exp((double)dw) * wa;  // correctly-rounded f32 exp
  float ph = (float)exp((double)dh) * ha;
  float x1 = pcx - 0.5f * pw, y1 = pcy - 0.5f * ph;
  float x2 = pcx + 0.5f * pw, y2 = pcy + 0.5f * ph;
  x1 = fminf(fmaxf(x1, 0.0f), 1024.0f);
  x2 = fminf(fmaxf(x2, 0.0f), 1024.0f);
  y1 = fminf(fmaxf(y1, 0.0f), 768.0f);
  y2 = fminf(fmaxf(y2, 0.0f), 768.0f);
  boxes[(size_t)g * 4 + 0] = x1;
  boxes[(size_t)g * 4 + 1] = y1;
  boxes[(size_t)g * 4 + 2] = x2;
  boxes[(size_t)g * 4 + 3] = y2;
  float s = (float)(1.0 / (1.0 + exp(-(double)o)));  // correctly-rounded sigmoid
  bool valid = ((x2 - x1) >= 1.0f) && ((y2 - y1) >= 1.0f) && (s >= 0.0f);
  sprime[g] = valid ? s : -1.0f;
  float mx = fmaxf(fmaxf(x1, y1), fmaxf(x2, y2));
  atomicMax((unsigned int*)&maxv[b], __float_as_uint(mx));  // coords >= 0 -> uint order ok
}

// ---------------------------------------------------------------------------
// K3: per-image stable sort of 4576 entries by (s' desc, pos asc); gather
// ---------------------------------------------------------------------------
__global__ __launch_bounds__(1024) void k_sort(const float* __restrict__ sprime,
                                               const float* __restrict__ boxes,
                                               float* __restrict__ score_sorted,
                                               float* __restrict__ boxes_sorted,
                                               int* __restrict__ lvl_sorted) {
  int b = blockIdx.x, tid = threadIdx.x;
  __shared__ unsigned long long skey[8192];  // 64 KB
  for (int e = tid; e < 8192; e += 1024) {
    if (e < KTOT) {
      unsigned int m = mono(sprime[b * KTOT + e]);
      skey[e] = ((unsigned long long)m << 32) | (unsigned int)(8191 - e);  // tie: smaller pos wins
    } else {
      skey[e] = 0ull;  // below mono(-1.0) = 0x407FFFFF
    }
  }
  __syncthreads();
  bitonic_sort(skey, 8192, tid, 1024);
  for (int j = tid; j < KTOT; j += 1024) {
    unsigned long long e = skey[8191 - j];  // rank j in descending order
    int p = 8191 - (int)(e & 0xFFFFFFFFull);
    score_sorted[b * KTOT + j] = sprime[b * KTOT + p];
    int lv = (p < 1000) ? 0 : (p < 2000) ? 1 : (p < 3000) ? 2 : (p < 4000) ? 3 : 4;
    lvl_sorted[b * KTOT + j] = lv;
    for (int c = 0; c < 4; ++c)
      boxes_sorted[((size_t)(b * KTOT + j)) * 4 + c] = boxes[((size_t)(b * KTOT + p)) * 4 + c];
  }
}

// ---------------------------------------------------------------------------
// K4: greedy NMS. Cross-level IoU is exactly 0 (offset gap >= 1), so the scan
// decomposes into 5 independent per-level problems -> 40 parallel blocks.
// Offsets still applied (rounding must match the reference's nb coordinates).
// ---------------------------------------------------------------------------
__global__ __launch_bounds__(256) void k_nms(const float* __restrict__ boxes_sorted,
                                             const float* __restrict__ score_sorted,
                                             const int* __restrict__ lvl_sorted,
                                             const float* __restrict__ maxv,
                                             int* __restrict__ keep_g) {
  int bx = blockIdx.x;
  int b = bx / NLEV, l = bx % NLEV;
  int tid = threadIdx.x;
  __shared__ float lx1[1000], ly1[1000], lx2[1000], ly2[1000], lar[1000];
  __shared__ int lkeep[1000], lpos[1000];
  __shared__ int s_wcnt[4], s_base;
  float off = (float)l * (maxv[b] + 1.0f);
  if (tid == 0) s_base = 0;
  __syncthreads();
  // ordered compaction of this level's entries (in sorted order)
  for (int chunk = 0; chunk < KTOT; chunk += 256) {
    int j = chunk + tid;
    bool match = (j < KTOT) && (lvl_sorted[b * KTOT + j] == l);
    unsigned long long mb = __ballot(match);
    if ((tid & 63) == 0) s_wcnt[tid >> 6] = __popcll(mb);
    __syncthreads();
    int rank = s_base + __popcll(mb & ((1ull << (tid & 63)) - 1ull));
    for (int w = 0; w < (tid >> 6); ++w) rank += s_wcnt[w];
    if (match) {
      const float* bp = boxes_sorted + ((size_t)(b * KTOT + j)) * 4;
      float x1 = bp[0] + off, y1 = bp[1] + off, x2 = bp[2] + off, y2 = bp[3] + off;
      lx1[rank] = x1; ly1[rank] = y1; lx2[rank] = x2; ly2[rank] = y2;
      lar[rank] = (x2 - x1) * (y2 - y1);
      lkeep[rank] = (score_sorted[b * KTOT + j] >= 0.0f) ? 1 : 0;  // invalid -> -1
      lpos[rank] = j;
    }
    __syncthreads();
    if (tid == 0) s_base += s_wcnt[0] + s_wcnt[1] + s_wcnt[2] + s_wcnt[3];
    __syncthreads();
  }
  int m = s_base;  // == k_l
  // greedy scan (matches lax.scan semantics within this level)
  for (int i = 0; i < m; ++i) {
    __syncthreads();
    if (!lkeep[i]) continue;  // uniform: all threads read same LDS after barrier
    float bx1 = lx1[i], by1 = ly1[i], bx2 = lx2[i], by2 = ly2[i], ba = lar[i];
    for (int j = i + 1 + tid; j < m; j += 256) {
      if (!lkeep[j]) continue;
      float xx1 = fmaxf(bx1, lx1[j]), yy1 = fmaxf(by1, ly1[j]);
      float xx2 = fminf(bx2, lx2[j]), yy2 = fminf(by2, ly2[j]);
      float w = fmaxf(xx2 - xx1, 0.0f), h = fmaxf(yy2 - yy1, 0.0f);
      float inter = w * h;
      float denom = fmaxf(ba + lar[j] - inter, 1e-9f);
      if (inter / denom > 0.7f) lkeep[j] = 0;
    }
  }
  __syncthreads();
  for (int j = tid; j < m; j += 256) keep_g[b * KTOT + lpos[j]] = lkeep[j];
}

// ---------------------------------------------------------------------------
// K5: emit first 1000 kept (in global sorted order) per image; zero-pad rest
// ---------------------------------------------------------------------------
__global__ __launch_bounds__(256) void k_out(const float* __restrict__ boxes_sorted,
                                             const float* __restrict__ score_sorted,
                                             const int* __restrict__ keep_g,
                                             float* __restrict__ out) {
  int b = blockIdx.x, tid = threadIdx.x;
  __shared__ int s_wcnt[4], s_base;
  for (int i = tid; i < 5000; i += 256) out[(size_t)b * 5000 + i] = 0.0f;
  if (tid == 0) s_base = 0;
  __syncthreads();
  for (int chunk = 0; chunk < KTOT; chunk += 256) {
    int j = chunk + tid;
    bool match = (j < KTOT) && (keep_g[b * KTOT + j] != 0);
    unsigned long long mb = __ballot(match);
    if ((tid & 63) == 0) s_wcnt[tid >> 6] = __popcll(mb);
    __syncthreads();
    int rank = s_base + __popcll(mb & ((1ull << (tid & 63)) - 1ull));
    for (int w = 0; w < (tid >> 6); ++w) rank += s_wcnt[w];
    if (match && rank < 1000) {
      const float* bp = boxes_sorted + ((size_t)(b * KTOT + j)) * 4;
      float* op = out + ((size_t)(b * 1000 + rank)) * 5;
      op[0] = bp[0]; op[1] = bp[1]; op[2] = bp[2]; op[3] = bp[3];
      op[4] = score_sorted[b * KTOT + j];
    }
    __syncthreads();
    if (tid == 0) s_base += s_wcnt[0] + s_wcnt[1] + s_wcnt[2] + s_wcnt[3];
    __syncthreads();
  }
}

extern "C" void kernel_launch(void* const* d_in, const int* in_sizes, int n_in,
                              void* d_out, int out_size, void* d_ws, size_t ws_size,
                              hipStream_t stream) {
  const float* obj     = (const float*)d_in[0];
  const float* deltas  = (const float*)d_in[1];
  const float* anchors = (const float*)d_in[2];
  float* out = (float*)d_out;

  // workspace layout (~2.1 MB)
  int*   sel_idx      = (int*)d_ws;                          // [8*4576]
  float* boxes        = (float*)(sel_idx + BATCH * KTOT);    // [8*4576*4]
  float* sprime       = boxes + (size_t)BATCH * KTOT * 4;    // [8*4576]
  float* maxv         = sprime + BATCH * KTOT;               // [8]
  float* score_sorted = maxv + BATCH;                        // [8*4576]
  float* boxes_sorted = score_sorted + BATCH * KTOT;         // [8*4576*4]
  int*   lvl_sorted   = (int*)(boxes_sorted + (size_t)BATCH * KTOT * 4);  // [8*4576]
  int*   keep_g       = lvl_sorted + BATCH * KTOT;           // [8*4576]

  hipLaunchKernelGGL(k_topk, dim3(BATCH * NLEV), dim3(1024), 0, stream, obj, sel_idx, maxv);
  hipLaunchKernelGGL(k_decode, dim3((BATCH * KTOT + 255) / 256), dim3(256), 0, stream,
                     obj, deltas, anchors, sel_idx, boxes, sprime, maxv);
  hipLaunchKernelGGL(k_sort, dim3(BATCH), dim3(1024), 0, stream,
                     sprime, boxes, score_sorted, boxes_sorted, lvl_sorted);
  hipLaunchKernelGGL(k_nms, dim3(BATCH * NLEV), dim3(256), 0, stream,
                     boxes_sorted, score_sorted, lvl_sorted, maxv, keep_g);
  hipLaunchKernelGGL(k_out, dim3(BATCH), dim3(256), 0, stream,
                     boxes_sorted, score_sorted, keep_g, out);
}